// Round 5
// baseline (9933.946 us; speedup 1.0000x reference)
//
#include <hip/hip_runtime.h>
#include <hip/hip_cooperative_groups.h>

namespace coop = cooperative_groups;

// PressureProjection on MI355X — round 11.
// R10 post-mortem: 2164us (best). All per-dispatch times <205us; the CG loop's
// 41 dispatches dominate (~1250us). matvec runs ~1.5TB/s effective ->
// latency/launch-bound, not BW-bound.
// R11: persistent cooperative CG kernel (node_setup + 20 iters fused).
//  * diag/minv/phi/r/p/ap live in REGISTERS across the whole solve; only z
//    is published per iteration (needed for the gather). 2 grid.sync/iter.
//  * removes 41 launches + ~500MB of dense round-trip traffic; unroll-2
//    edge loop for gather MLP.
//  * co-residency: 489 blk x 16 waves = 7824 <= 8192; launch_bounds(1024,8)
//    pins VGPR<=64 for 2 blocks/CU. hipLaunchCooperativeKernel failure ->
//    exact R10 fallback path (kernels kept verbatim).
// Predicted: one cg_fused dispatch ~850-950us (FETCH ~1.4GB) replacing
// ~1250us of small dispatches; total 2164 -> ~1750-1850us.

#define TPB 256
#define TPB_A 1024
#define TPB_B 1024       // bucket kernels: 1 thread per node in bucket
#define KB 2048          // grid for dense kernels & partial arrays
#define NBLK 256         // chunks for bucket sort
#define BSHIFT 10        // bucket = dst >> 10 (1024 nodes per bucket)
#define BSIZE 1024
#define MAXNB 512        // max coarse buckets (N <= 524288)
#define CG_ITERS 20
#define TOL2 1e-8f       // (CG_TOL=1e-4)^2

typedef unsigned long long ull;

struct Sum3 { float a, b, c; };

// block-wide sums of three arrays (independent lengths), broadcast
template <int BS>
__device__ inline Sum3 block_sum3n_bcast(const float* __restrict__ A, int nA,
                                         const float* __restrict__ B, int nB,
                                         const float* __restrict__ C, int nC) {
  float va = 0.f, vb = 0.f, vc = 0.f;
  for (int k = threadIdx.x; k < nA; k += BS) va += A[k];
  for (int k = threadIdx.x; k < nB; k += BS) vb += B[k];
  for (int k = threadIdx.x; k < nC; k += BS) vc += C[k];
#pragma unroll
  for (int o = 32; o; o >>= 1) {
    va += __shfl_down(va, o, 64);
    vb += __shfl_down(vb, o, 64);
    vc += __shfl_down(vc, o, 64);
  }
  __shared__ float sa[BS / 64], sb[BS / 64], sc[BS / 64], bc[3];
  int lane = threadIdx.x & 63, wid = threadIdx.x >> 6;
  if (lane == 0) { sa[wid] = va; sb[wid] = vb; sc[wid] = vc; }
  __syncthreads();
  if (threadIdx.x == 0) {
    float ta = 0.f, tb = 0.f, tc = 0.f;
#pragma unroll
    for (int k = 0; k < BS / 64; k++) { ta += sa[k]; tb += sb[k]; tc += sc[k]; }
    bc[0] = ta; bc[1] = tb; bc[2] = tc;
  }
  __syncthreads();
  Sum3 r{bc[0], bc[1], bc[2]};
  __syncthreads();
  return r;
}

template <int BS>
__device__ inline void block_reduce1_store(float v1, float* d1) {
#pragma unroll
  for (int o = 32; o; o >>= 1) v1 += __shfl_down(v1, o, 64);
  __shared__ float s1[BS / 64];
  int lane = threadIdx.x & 63, wid = threadIdx.x >> 6;
  if (lane == 0) s1[wid] = v1;
  __syncthreads();
  if (threadIdx.x == 0) {
    float t1 = 0.f;
#pragma unroll
    for (int k = 0; k < BS / 64; k++) t1 += s1[k];
    *d1 = t1;
  }
}

template <int BS>
__device__ inline void block_reduce2_store(float v1, float v2, float* d1, float* d2) {
#pragma unroll
  for (int o = 32; o; o >>= 1) {
    v1 += __shfl_down(v1, o, 64);
    v2 += __shfl_down(v2, o, 64);
  }
  __shared__ float s1[BS / 64], s2[BS / 64];
  int lane = threadIdx.x & 63, wid = threadIdx.x >> 6;
  if (lane == 0) { s1[wid] = v1; s2[wid] = v2; }
  __syncthreads();
  if (threadIdx.x == 0) {
    float t1 = 0.f, t2 = 0.f;
#pragma unroll
    for (int k = 0; k < BS / 64; k++) { t1 += s1[k]; t2 += s2[k]; }
    *d1 = t1;
    *d2 = t2;
  }
}

// ---- pass A0: LDS histogram (+ optional coalesced WF={w,flux} write) ----
__global__ __launch_bounds__(TPB_A) void hist_wf(
    const int* __restrict__ ei, const float* __restrict__ u_hat,
    const float* __restrict__ fn, const float* __restrict__ fa,
    const float* __restrict__ fd, unsigned* __restrict__ mat,
    float2* __restrict__ wf, int E, int NB, int chunk) {
  __shared__ unsigned cntL[MAXNB];
  for (int i = threadIdx.x; i < NB; i += TPB_A) cntL[i] = 0;
  __syncthreads();
  int blk = blockIdx.x;
  int e0 = blk * chunk, e1 = min(E, e0 + chunk);
  for (int e = e0 + threadIdx.x; e < e1; e += TPB_A) {
    int d = ei[E + e];
    atomicAdd(&cntL[((unsigned)d) >> BSHIFT], 1u);
    if (wf) {
      int s = ei[e];
      float area = fa[e];
      float w = area / fmaxf(fd[e], 1e-8f);
      float ux = 0.5f * (u_hat[3 * s]     + u_hat[3 * d]);
      float uy = 0.5f * (u_hat[3 * s + 1] + u_hat[3 * d + 1]);
      float uz = 0.5f * (u_hat[3 * s + 2] + u_hat[3 * d + 2]);
      float flux = (ux * fn[3 * e] + uy * fn[3 * e + 1] + uz * fn[3 * e + 2]) * area;
      wf[e] = make_float2(w, flux);
    }
  }
  __syncthreads();
  for (int b = threadIdx.x; b < NB; b += TPB_A)
    mat[(size_t)b * NBLK + blk] = cntL[b];
}

// ---- scan (1024 elems / block) ----
__global__ __launch_bounds__(TPB) void scan_blocks(
    const unsigned* __restrict__ cnt, unsigned* __restrict__ offs,
    unsigned* __restrict__ btot, int n) {
  __shared__ unsigned sd[TPB];
  int t = threadIdx.x;
  int base = blockIdx.x * 1024 + t * 4;
  unsigned v0 = 0, v1 = 0, v2 = 0, v3 = 0;
  if (base + 0 < n) v0 = cnt[base + 0];
  if (base + 1 < n) v1 = cnt[base + 1];
  if (base + 2 < n) v2 = cnt[base + 2];
  if (base + 3 < n) v3 = cnt[base + 3];
  unsigned local = v0 + v1 + v2 + v3;
  sd[t] = local;
  __syncthreads();
  for (int o = 1; o < TPB; o <<= 1) {
    unsigned x = (t >= o) ? sd[t - o] : 0u;
    __syncthreads();
    sd[t] += x;
    __syncthreads();
  }
  unsigned excl = sd[t] - local;
  if (base + 0 < n) offs[base + 0] = excl; excl += v0;
  if (base + 1 < n) offs[base + 1] = excl; excl += v1;
  if (base + 2 < n) offs[base + 2] = excl; excl += v2;
  if (base + 3 < n) offs[base + 3] = excl;
  if (t == TPB - 1) btot[blockIdx.x] = sd[TPB - 1];
}

__global__ __launch_bounds__(512) void scan_totals(unsigned* __restrict__ btot, int nb) {
  __shared__ unsigned sd[512];
  int t = threadIdx.x;
  unsigned v = (t < nb) ? btot[t] : 0u;
  sd[t] = v;
  __syncthreads();
  for (int o = 1; o < 512; o <<= 1) {
    unsigned x = (t >= o) ? sd[t - o] : 0u;
    __syncthreads();
    sd[t] += x;
    __syncthreads();
  }
  if (t < nb) btot[t] = sd[t] - v;  // exclusive
}

__global__ __launch_bounds__(TPB) void scan_add(
    unsigned* __restrict__ offs, const unsigned* __restrict__ btot,
    int n, unsigned total) {
  int i = blockIdx.x * TPB + threadIdx.x;
  if (i < n) offs[i] += btot[i >> 10];
  if (i == 0) offs[n] = total;
}

// ---- pass A1: place edges as 16-B {hi, w, flux, eid} ----
__global__ __launch_bounds__(TPB_A) void bucket_place(
    const int* __restrict__ ei, const float* __restrict__ u_hat,
    const float* __restrict__ fn, const float* __restrict__ fa,
    const float* __restrict__ fd, const float2* __restrict__ wf,
    const unsigned* __restrict__ offs, uint4* __restrict__ A16,
    int E, int NB, int chunk) {
  __shared__ unsigned cntL[MAXNB];
  __shared__ unsigned offL[MAXNB];
  int blk = blockIdx.x;
  for (int i = threadIdx.x; i < NB; i += TPB_A) {
    cntL[i] = 0;
    offL[i] = offs[(size_t)i * NBLK + blk];
  }
  __syncthreads();
  int e0 = blk * chunk, e1 = min(E, e0 + chunk);
  for (int e = e0 + threadIdx.x; e < e1; e += TPB_A) {
    int s = ei[e], d = ei[E + e];
    float w, flux;
    if (wf) {
      float2 v = wf[e];
      w = v.x; flux = v.y;
    } else {
      float area = fa[e];
      w = area / fmaxf(fd[e], 1e-8f);
      float ux = 0.5f * (u_hat[3 * s]     + u_hat[3 * d]);
      float uy = 0.5f * (u_hat[3 * s + 1] + u_hat[3 * d + 1]);
      float uz = 0.5f * (u_hat[3 * s + 2] + u_hat[3 * d + 2]);
      flux = (ux * fn[3 * e] + uy * fn[3 * e + 1] + uz * fn[3 * e + 2]) * area;
    }
    unsigned b = ((unsigned)d) >> BSHIFT;
    unsigned dl = ((unsigned)d) & (BSIZE - 1u);
    unsigned r = atomicAdd(&cntL[b], 1u);
    unsigned pos = offL[b] + r;
    unsigned hi = (dl << 19) | (unsigned)s;
    A16[(size_t)pos] = make_uint4(hi, __float_as_uint(w),
                                  __float_as_uint(flux), (unsigned)e);
  }
}

// ===================== FUSED COOPERATIVE CG =====================
// block b = bucket b; thread = node (b<<10)+tid. State in registers.
__global__ __launch_bounds__(TPB_B, 8) void cg_fused(
    const uint4* __restrict__ A16, ull* __restrict__ A8,
    const unsigned* __restrict__ offs, const float* __restrict__ cv,
    float* __restrict__ zg, float* __restrict__ phi_g,
    float* __restrict__ pap_c, float* __restrict__ rz_c,
    float* __restrict__ rr_c, int N, int NB, int iters) {
  coop::grid_group grid = coop::this_grid();
  __shared__ float sAcc[TPB_B];
  __shared__ float sB[TPB_B];
  __shared__ float sR1[TPB_B / 64], sR2[TPB_B / 64];
  __shared__ float sBC[2];

  const int b = blockIdx.x;
  const int tid = threadIdx.x;
  const int node = (b << BSHIFT) + tid;
  const bool valid = (node < N);
  const unsigned jb = offs[(size_t)b * NBLK];
  const unsigned je = offs[(size_t)(b + 1) * NBLK];
  const int lane = tid & 63, wid = tid >> 6;

  // ---- init: bucket sums of w/flux from A16; split A8 hot stream ----
  sAcc[tid] = 0.f;
  sB[tid] = 0.f;
  __syncthreads();
  {
    const ull* q = (const ull*)A16;
    for (unsigned j = jb + tid; j < je; j += TPB_B) {
      ull a = __builtin_nontemporal_load(&q[(size_t)2 * j]);      // {hi, w}
      ull c = __builtin_nontemporal_load(&q[(size_t)2 * j + 1]);  // {flux, eid}
      unsigned hi = (unsigned)a;
      atomicAdd(&sAcc[hi >> 19], __uint_as_float((unsigned)(a >> 32)));
      atomicAdd(&sB[hi >> 19], __uint_as_float((unsigned)c));
      if (A8) A8[(size_t)j] = a;
    }
  }
  __syncthreads();

  float diag_n = 0.f, minv_n = 0.f, phi_n = 0.f;
  float r_n = 0.f, z_n = 0.f, p_n = 0.f, ap_n = 0.f;
  if (valid) {
    float wsum = sAcc[tid];
    float vol = fmaxf(cv[node], 1e-12f);
    float bval = sB[tid] / vol;
    diag_n = wsum;
    minv_n = 1.0f / fmaxf(wsum, 1e-8f);
    r_n = bval;
    z_n = minv_n * bval;
    zg[node] = z_n;
  }
  __syncthreads();   // sAcc/sB reuse below

  // rz0/rr0 partials
  {
    float v1 = valid ? r_n * z_n : 0.f;
    float v2 = valid ? r_n * r_n : 0.f;
#pragma unroll
    for (int o = 32; o; o >>= 1) { v1 += __shfl_down(v1, o, 64); v2 += __shfl_down(v2, o, 64); }
    if (lane == 0) { sR1[wid] = v1; sR2[wid] = v2; }
    __syncthreads();
    if (tid == 0) {
      float t1 = 0.f, t2 = 0.f;
#pragma unroll
      for (int k = 0; k < TPB_B / 64; k++) { t1 += sR1[k]; t2 += sR2[k]; }
      rz_c[b] = t1; rr_c[b] = t2;
    }
    __syncthreads();
  }
  __threadfence();
  grid.sync();

  // global sums of rz/rr
  float rz_cur, rr_cur, rz_prev = 0.f;
  {
    float v1 = 0.f, v2 = 0.f;
    for (int k = tid; k < NB; k += TPB_B) { v1 += rz_c[k]; v2 += rr_c[k]; }
#pragma unroll
    for (int o = 32; o; o >>= 1) { v1 += __shfl_down(v1, o, 64); v2 += __shfl_down(v2, o, 64); }
    if (lane == 0) { sR1[wid] = v1; sR2[wid] = v2; }
    __syncthreads();
    if (tid == 0) {
      float t1 = 0.f, t2 = 0.f;
#pragma unroll
      for (int k = 0; k < TPB_B / 64; k++) { t1 += sR1[k]; t2 += sR2[k]; }
      sBC[0] = t1; sBC[1] = t2;
    }
    __syncthreads();
    rz_cur = sBC[0]; rr_cur = sBC[1];
    __syncthreads();
  }

  for (int it = 0; it < iters; ++it) {
    // ---- edge gather: acc = sum w * z[src] per local node ----
    sAcc[tid] = 0.f;
    __syncthreads();
    if (A8) {
      unsigned j = jb + tid;
      for (; j + TPB_B < je; j += 2 * TPB_B) {
        ull v0 = __builtin_nontemporal_load(&A8[(size_t)j]);
        ull v1 = __builtin_nontemporal_load(&A8[(size_t)j + TPB_B]);
        unsigned h0 = (unsigned)v0, h1 = (unsigned)v1;
        float z0 = zg[h0 & 0x7FFFFu];
        float z1 = zg[h1 & 0x7FFFFu];
        atomicAdd(&sAcc[h0 >> 19], __uint_as_float((unsigned)(v0 >> 32)) * z0);
        atomicAdd(&sAcc[h1 >> 19], __uint_as_float((unsigned)(v1 >> 32)) * z1);
      }
      if (j < je) {
        ull v0 = __builtin_nontemporal_load(&A8[(size_t)j]);
        unsigned h0 = (unsigned)v0;
        atomicAdd(&sAcc[h0 >> 19],
                  __uint_as_float((unsigned)(v0 >> 32)) * zg[h0 & 0x7FFFFu]);
      }
    } else {
      const ull* q = (const ull*)A16;
      for (unsigned j = jb + tid; j < je; j += TPB_B) {
        ull v0 = __builtin_nontemporal_load(&q[(size_t)2 * j]);
        unsigned h0 = (unsigned)v0;
        atomicAdd(&sAcc[h0 >> 19],
                  __uint_as_float((unsigned)(v0 >> 32)) * zg[h0 & 0x7FFFFu]);
      }
    }
    __syncthreads();
    float az = valid ? (diag_n * z_n - sAcc[tid]) : 0.f;
    __syncthreads();   // sAcc free for reuse

    // ---- p/ap recurrence (registers) ----
    if (it == 0) {
      p_n = z_n; ap_n = az;
    } else if (rr_cur >= TOL2) {
      float beta = rz_cur / (rz_prev + 1e-12f);
      p_n = fmaf(beta, p_n, z_n);
      ap_n = fmaf(beta, ap_n, az);
    }

    // pap partial
    {
      float v1 = valid ? p_n * ap_n : 0.f;
#pragma unroll
      for (int o = 32; o; o >>= 1) v1 += __shfl_down(v1, o, 64);
      if (lane == 0) sR1[wid] = v1;
      __syncthreads();
      if (tid == 0) {
        float t1 = 0.f;
#pragma unroll
        for (int k = 0; k < TPB_B / 64; k++) t1 += sR1[k];
        pap_c[b] = t1;
      }
      __syncthreads();
    }
    __threadfence();
    grid.sync();

    // global pap sum
    float pap;
    {
      float v1 = 0.f;
      for (int k = tid; k < NB; k += TPB_B) v1 += pap_c[k];
#pragma unroll
      for (int o = 32; o; o >>= 1) v1 += __shfl_down(v1, o, 64);
      if (lane == 0) sR1[wid] = v1;
      __syncthreads();
      if (tid == 0) {
        float t1 = 0.f;
#pragma unroll
        for (int k = 0; k < TPB_B / 64; k++) t1 += sR1[k];
        sBC[0] = t1;
      }
      __syncthreads();
      pap = sBC[0];
      __syncthreads();
    }

    // ---- gated update (registers); publish z ----
    bool act = (rr_cur >= TOL2);
    float alpha = rz_cur / (pap + 1e-12f);
    if (act && valid) {
      phi_n = fmaf(alpha, p_n, phi_n);
      r_n = fmaf(-alpha, ap_n, r_n);
      z_n = minv_n * r_n;
      zg[node] = z_n;
    }

    // rz/rr partials for next iteration
    {
      float v1 = valid ? r_n * z_n : 0.f;
      float v2 = valid ? r_n * r_n : 0.f;
#pragma unroll
      for (int o = 32; o; o >>= 1) { v1 += __shfl_down(v1, o, 64); v2 += __shfl_down(v2, o, 64); }
      if (lane == 0) { sR1[wid] = v1; sR2[wid] = v2; }
      __syncthreads();
      if (tid == 0) {
        float t1 = 0.f, t2 = 0.f;
#pragma unroll
        for (int k = 0; k < TPB_B / 64; k++) { t1 += sR1[k]; t2 += sR2[k]; }
        rz_c[b] = t1; rr_c[b] = t2;
      }
      __syncthreads();
    }
    __threadfence();
    grid.sync();

    rz_prev = rz_cur;
    {
      float v1 = 0.f, v2 = 0.f;
      for (int k = tid; k < NB; k += TPB_B) { v1 += rz_c[k]; v2 += rr_c[k]; }
#pragma unroll
      for (int o = 32; o; o >>= 1) { v1 += __shfl_down(v1, o, 64); v2 += __shfl_down(v2, o, 64); }
      if (lane == 0) { sR1[wid] = v1; sR2[wid] = v2; }
      __syncthreads();
      if (tid == 0) {
        float t1 = 0.f, t2 = 0.f;
#pragma unroll
        for (int k = 0; k < TPB_B / 64; k++) { t1 += sR1[k]; t2 += sR2[k]; }
        sBC[0] = t1; sBC[1] = t2;
      }
      __syncthreads();
      rz_cur = sBC[0]; rr_cur = sBC[1];
      __syncthreads();
    }
  }

  if (valid) phi_g[node] = phi_n;
}

// ===================== R10 fallback kernels =====================
__global__ __launch_bounds__(TPB_B) void node_setup(
    const uint4* __restrict__ A16, ull* __restrict__ A8,
    const unsigned* __restrict__ offs, const float* __restrict__ cv,
    float* __restrict__ diag, float* __restrict__ minv,
    float* __restrict__ r, float* __restrict__ z, float* __restrict__ phi,
    float* __restrict__ rz_part, float* __restrict__ rr_part, int N, int NB) {
  __shared__ float wacc[TPB_B], facc[TPB_B];
  int b = blockIdx.x;
  float rzv = 0.f, rrv = 0.f;
  if (b < NB) {
    wacc[threadIdx.x] = 0.f;
    facc[threadIdx.x] = 0.f;
    __syncthreads();
    unsigned jb = offs[(size_t)b * NBLK], je = offs[(size_t)(b + 1) * NBLK];
    const ull* q = (const ull*)A16;
    for (unsigned j = jb + threadIdx.x; j < je; j += TPB_B) {
      ull a = __builtin_nontemporal_load(&q[(size_t)2 * j]);
      ull bq = __builtin_nontemporal_load(&q[(size_t)2 * j + 1]);
      unsigned hi = (unsigned)a;
      float w = __uint_as_float((unsigned)(a >> 32));
      float flux = __uint_as_float((unsigned)bq);
      atomicAdd(&wacc[hi >> 19], w);
      atomicAdd(&facc[hi >> 19], flux);
      if (A8) A8[(size_t)j] = a;
    }
    __syncthreads();
    int node = (b << BSHIFT) + threadIdx.x;
    if (node < N) {
      float wsum = wacc[threadIdx.x];
      float vol = fmaxf(cv[node], 1e-12f);
      float bval = facc[threadIdx.x] / vol;
      float mi = 1.0f / fmaxf(wsum, 1e-8f);
      diag[node] = wsum;
      minv[node] = mi;
      r[node] = bval;
      float zi = mi * bval;
      z[node] = zi;
      phi[node] = 0.f;
      rzv = bval * zi;
      rrv = bval * bval;
    }
  }
  block_reduce2_store<TPB_B>(rzv, rrv, &rz_part[blockIdx.x], &rr_part[blockIdx.x]);
}

__global__ __launch_bounds__(TPB_B) void matvec_az(
    const float* __restrict__ z, const float* __restrict__ diag,
    const unsigned* __restrict__ offs, const ull* __restrict__ A8,
    const uint4* __restrict__ A16,
    const float* __restrict__ p_old, float* __restrict__ p_new,
    const float* __restrict__ ap_old, float* __restrict__ ap_new,
    float* __restrict__ pap_part,
    const float* __restrict__ rzJ_part, const float* __restrict__ rzJm1_part,
    const float* __restrict__ rrJ_part, int N, int first) {
  __shared__ float acc[TPB_B];
  int b = blockIdx.x;
  acc[threadIdx.x] = 0.f;
  __syncthreads();
  unsigned jb = offs[(size_t)b * NBLK], je = offs[(size_t)(b + 1) * NBLK];
  if (A8) {
    for (unsigned j = jb + threadIdx.x; j < je; j += TPB_B) {
      ull v = __builtin_nontemporal_load(&A8[(size_t)j]);
      unsigned hi = (unsigned)v;
      float w = __uint_as_float((unsigned)(v >> 32));
      atomicAdd(&acc[hi >> 19], w * z[hi & 0x7FFFFu]);
    }
  } else {
    const ull* q = (const ull*)A16;
    for (unsigned j = jb + threadIdx.x; j < je; j += TPB_B) {
      ull v = __builtin_nontemporal_load(&q[(size_t)2 * j]);
      unsigned hi = (unsigned)v;
      float w = __uint_as_float((unsigned)(v >> 32));
      atomicAdd(&acc[hi >> 19], w * z[hi & 0x7FFFFu]);
    }
  }
  __syncthreads();
  float beta = 0.f;
  bool act = true;
  if (!first) {
    Sum3 s = block_sum3n_bcast<TPB_B>(rzJ_part, KB, rzJm1_part, KB, rrJ_part, KB);
    act = (s.c >= TOL2);
    beta = s.a / (s.b + 1e-12f);
  }
  float contrib = 0.f;
  int node = (b << BSHIFT) + threadIdx.x;
  if (node < N) {
    float zi = z[node];
    float az = diag[node] * zi - acc[threadIdx.x];
    float pn, apn;
    if (first)    { pn = zi;                          apn = az; }
    else if (act) { pn = fmaf(beta, p_old[node], zi); apn = fmaf(beta, ap_old[node], az); }
    else          { pn = p_old[node];                 apn = ap_old[node]; }
    p_new[node] = pn;
    ap_new[node] = apn;
    contrib = pn * apn;
  }
  block_reduce1_store<TPB_B>(contrib, &pap_part[b]);
}

__global__ __launch_bounds__(TPB) void cg_update(
    float* __restrict__ phi, float* __restrict__ r, const float* __restrict__ p,
    const float* __restrict__ ap, const float* __restrict__ minv,
    float* __restrict__ z,
    const float* __restrict__ pap_it, const float* __restrict__ rz_it,
    const float* __restrict__ rr_it, float* __restrict__ rz_next,
    float* __restrict__ rr_next, int N, int NB) {
  Sum3 s = block_sum3n_bcast<TPB>(pap_it, NB, rz_it, KB, rr_it, KB);
  bool act = (s.c >= TOL2);
  float alpha = s.b / (s.a + 1e-12f);
  float rzacc = 0.f, rracc = 0.f;
  for (int i = blockIdx.x * TPB + threadIdx.x; i < N; i += KB * TPB) {
    float ri = r[i];
    if (act) {
      phi[i] += alpha * p[i];
      ri -= alpha * ap[i];
      r[i] = ri;
    }
    float zi = minv[i] * ri;
    z[i] = zi;
    rzacc += ri * zi;
    rracc += ri * ri;
  }
  block_reduce2_store<TPB>(rzacc, rracc, &rz_next[blockIdx.x], &rr_next[blockIdx.x]);
}

// ---- pressure correction + output: per-bucket LDS grad accumulate ----
__global__ __launch_bounds__(TPB_B) void finalize(
    const float* __restrict__ u_hat, const float* __restrict__ cv,
    const float* __restrict__ phi, const unsigned* __restrict__ offs,
    const uint4* __restrict__ A16, const float* __restrict__ fn,
    float* __restrict__ out, int N, int NB) {
  __shared__ float gxa[TPB_B], gya[TPB_B], gza[TPB_B];
  int b = blockIdx.x;
  if (b >= NB) return;
  gxa[threadIdx.x] = 0.f;
  gya[threadIdx.x] = 0.f;
  gza[threadIdx.x] = 0.f;
  __syncthreads();
  unsigned jb = offs[(size_t)b * NBLK], je = offs[(size_t)(b + 1) * NBLK];
  const ull* q = (const ull*)A16;
  for (unsigned j = jb + threadIdx.x; j < je; j += TPB_B) {
    ull a = __builtin_nontemporal_load(&q[(size_t)2 * j]);      // {hi, w}
    ull bq = __builtin_nontemporal_load(&q[(size_t)2 * j + 1]); // {flux, eid}
    unsigned hi = (unsigned)a;
    float w = __uint_as_float((unsigned)(a >> 32));
    int e = (int)(unsigned)(bq >> 32);
    float t = w * phi[hi & 0x7FFFFu];
    int dl = hi >> 19;
    atomicAdd(&gxa[dl], t * fn[3 * e]);
    atomicAdd(&gya[dl], t * fn[3 * e + 1]);
    atomicAdd(&gza[dl], t * fn[3 * e + 2]);
  }
  __syncthreads();
  int node = (b << BSHIFT) + threadIdx.x;
  if (node < N) {
    float iv = 1.0f / fmaxf(cv[node], 1e-12f);
    out[3 * node]     = u_hat[3 * node]     - gxa[threadIdx.x] * iv;
    out[3 * node + 1] = u_hat[3 * node + 1] - gya[threadIdx.x] * iv;
    out[3 * node + 2] = u_hat[3 * node + 2] - gza[threadIdx.x] * iv;
    out[3 * N + node] = phi[node];
  }
}

extern "C" void kernel_launch(void* const* d_in, const int* in_sizes, int n_in,
                              void* d_out, int out_size, void* d_ws, size_t ws_size,
                              hipStream_t stream) {
  const float* u_hat = (const float*)d_in[0];
  const int*   ei    = (const int*)d_in[1];
  const float* fn    = (const float*)d_in[2];
  const float* fa    = (const float*)d_in[3];
  const float* fd    = (const float*)d_in[4];
  const float* cv    = (const float*)d_in[5];
  float* out = (float*)d_out;

  const int N = in_sizes[0] / 3;   // 500,000
  const int E = in_sizes[1] / 2;   // 8,000,000
  const int NB = (N + BSIZE - 1) >> BSHIFT;  // coarse buckets (489)
  const int NS = NB * NBLK;        // scan length (125,184)
  const int chunk = (E + NBLK - 1) / NBLK;

  // ---- workspace bump allocator (256B aligned) ----
  char* base = (char*)d_ws;
  size_t off = 0;
  auto alloc = [&](size_t bytes) -> void* {
    void* ptr = base + off;
    off = (off + bytes + 255) & ~size_t(255);
    return ptr;
  };
  unsigned* mat   = (unsigned*)alloc((size_t)NS * 4);
  unsigned* offs  = (unsigned*)alloc((size_t)(NS + 1) * 4);
  unsigned* btot  = (unsigned*)alloc(512 * 4);
  float*    diag  = (float*)alloc((size_t)N * 4);
  float*    minv  = (float*)alloc((size_t)N * 4);
  float*    phi   = (float*)alloc((size_t)N * 4);
  float*    rvec  = (float*)alloc((size_t)N * 4);
  float*    zvec  = (float*)alloc((size_t)N * 4);
  float*    pA    = (float*)alloc((size_t)N * 4);
  float*    pB    = (float*)alloc((size_t)N * 4);
  float*    apA   = (float*)alloc((size_t)N * 4);
  float*    apB   = (float*)alloc((size_t)N * 4);
  float*    rzrr  = (float*)alloc((size_t)(2 * (CG_ITERS + 1)) * KB * 4);
  float*    papp  = (float*)alloc((size_t)CG_ITERS * KB * 4);
  float*    papc  = (float*)alloc(512 * 4);   // fused partials (NB <= 512)
  float*    rzc   = (float*)alloc(512 * 4);
  float*    rrc   = (float*)alloc(512 * 4);
  uint4*    A16   = (uint4*)alloc((size_t)E * 16);      // base ≈ 148 MB (proven)
  ull* A8 = nullptr;                                    // tier 1: +64 MB
  if (off + (size_t)E * 8 + 256 <= ws_size) A8 = (ull*)alloc((size_t)E * 8);
  float2* WF = nullptr;                                 // tier 2: +64 MB
  if (off + (size_t)E * 8 + 256 <= ws_size) WF = (float2*)alloc((size_t)E * 8);
  (void)n_in; (void)out_size;

  auto rz_part = [&](int it) { return rzrr + (size_t)(2 * it) * KB; };
  auto rr_part = [&](int it) { return rzrr + (size_t)(2 * it + 1) * KB; };
  auto pap_part = [&](int it) { return papp + (size_t)it * KB; };

  const int nbScan = (NS + 1023) / 1024;          // 123 <= 512
  const int gridScanAdd = (NS + TPB - 1) / TPB;

  hist_wf<<<NBLK, TPB_A, 0, stream>>>(ei, u_hat, fn, fa, fd, mat, WF,
                                      E, NB, chunk);

  scan_blocks<<<nbScan, TPB, 0, stream>>>(mat, offs, btot, NS);
  scan_totals<<<1, 512, 0, stream>>>(btot, nbScan);
  scan_add<<<gridScanAdd, TPB, 0, stream>>>(offs, btot, NS, (unsigned)E);

  bucket_place<<<NBLK, TPB_A, 0, stream>>>(ei, u_hat, fn, fa, fd, WF, offs,
                                           A16, E, NB, chunk);

  // ---- try fused cooperative CG; fall back to R10 path on failure ----
  int iters = CG_ITERS;
  int N_ = N, NB_ = NB;
  void* kargs[] = {
    (void*)&A16, (void*)&A8, (void*)&offs, (void*)&cv,
    (void*)&zvec, (void*)&phi, (void*)&papc, (void*)&rzc, (void*)&rrc,
    (void*)&N_, (void*)&NB_, (void*)&iters
  };
  hipError_t cerr = hipLaunchCooperativeKernel(
      (void*)cg_fused, dim3(NB), dim3(TPB_B), kargs, 0, stream);
  if (cerr != hipSuccess) {
    (void)hipGetLastError();  // clear error state
    node_setup<<<KB, TPB_B, 0, stream>>>(A16, A8, offs, cv, diag, minv,
                                         rvec, zvec, phi,
                                         rz_part(0), rr_part(0), N, NB);
    float* pbuf[2]  = {pA, pB};
    float* apbuf[2] = {apA, apB};
    for (int it = 0; it < CG_ITERS; it++) {
      int ni = it & 1;
      float* pn  = pbuf[ni];
      float* apn = apbuf[ni];
      const float* po  = pbuf[1 - ni];
      const float* apo = apbuf[1 - ni];
      int first = (it == 0) ? 1 : 0;
      matvec_az<<<NB, TPB_B, 0, stream>>>(zvec, diag, offs, A8, A16,
                                          po, pn, apo, apn, pap_part(it),
                                          rz_part(it), rz_part(it > 0 ? it - 1 : 0),
                                          rr_part(it), N, first);
      cg_update<<<KB, TPB, 0, stream>>>(phi, rvec, pn, apn, minv, zvec,
                                        pap_part(it), rz_part(it), rr_part(it),
                                        rz_part(it + 1), rr_part(it + 1), N, NB);
    }
  }

  finalize<<<NB, TPB_B, 0, stream>>>(u_hat, cv, phi, offs, A16,
                                     fn, out, N, NB);
}

// Round 6
// 3355.639 us; speedup vs baseline: 2.9604x; 2.9604x over previous
//
#include <hip/hip_runtime.h>

// PressureProjection on MI355X — round 12.
// R11 post-mortem: cooperative grid.sync costs ~150us on MI355X (62 syncs =
// 9.3ms, VALUBusy 0.7%) -> persistent-kernel CG is dead; kernel boundaries
// ARE the cheap global barrier. Revert to R10 shell (2164us proven).
// R10 analysis: matvec 45us vs ~20us traffic floor; gap = 8M LDS atomicAdds
// (~31K/CU x ~3cyc ~= 40us; SQ_LDS_BANK_CONFLICT 1.2M corroborates).
// R12: full counting-sort to CSR in node_setup (LDS 1024-bin histogram +
// scan + placement; one extra 128MB A16 re-read ~20us one-time) -> A8 sorted
// by dst + rowptr[N+1]. matvec: thread n walks its own row (contiguous 8B
// {src,w} entries, 2-way unroll), gathers z[src] (4B, 2MB L2-resident,
// footprint UNCHANGED per R8 lesson), register accumulate. No LDS atomics.
// launch_bounds(1024,8) keeps 2 blocks/CU for latency hiding.
// Predicted: matvec 45->~25us (LDS_BANK_CONFLICT -> ~0), total 2164->~1800.
// Falsifier: matvec >=40us with conflicts~0 => z-gather-latency bound.

#define TPB 256
#define TPB_A 1024
#define TPB_B 1024       // bucket kernels: 1 thread per node in bucket
#define KB 2048          // grid for dense kernels & partial arrays
#define NBLK 256         // chunks for bucket sort
#define BSHIFT 10        // bucket = dst >> 10 (1024 nodes per bucket)
#define BSIZE 1024
#define MAXNB 512        // max coarse buckets (N <= 524288)
#define CG_ITERS 20
#define TOL2 1e-8f       // (CG_TOL=1e-4)^2

typedef unsigned long long ull;

struct Sum3 { float a, b, c; };

// block-wide sums of three arrays (independent lengths), broadcast
template <int BS>
__device__ inline Sum3 block_sum3n_bcast(const float* __restrict__ A, int nA,
                                         const float* __restrict__ B, int nB,
                                         const float* __restrict__ C, int nC) {
  float va = 0.f, vb = 0.f, vc = 0.f;
  for (int k = threadIdx.x; k < nA; k += BS) va += A[k];
  for (int k = threadIdx.x; k < nB; k += BS) vb += B[k];
  for (int k = threadIdx.x; k < nC; k += BS) vc += C[k];
#pragma unroll
  for (int o = 32; o; o >>= 1) {
    va += __shfl_down(va, o, 64);
    vb += __shfl_down(vb, o, 64);
    vc += __shfl_down(vc, o, 64);
  }
  __shared__ float sa[BS / 64], sb[BS / 64], sc[BS / 64], bc[3];
  int lane = threadIdx.x & 63, wid = threadIdx.x >> 6;
  if (lane == 0) { sa[wid] = va; sb[wid] = vb; sc[wid] = vc; }
  __syncthreads();
  if (threadIdx.x == 0) {
    float ta = 0.f, tb = 0.f, tc = 0.f;
#pragma unroll
    for (int k = 0; k < BS / 64; k++) { ta += sa[k]; tb += sb[k]; tc += sc[k]; }
    bc[0] = ta; bc[1] = tb; bc[2] = tc;
  }
  __syncthreads();
  Sum3 r{bc[0], bc[1], bc[2]};
  __syncthreads();
  return r;
}

template <int BS>
__device__ inline void block_reduce1_store(float v1, float* d1) {
#pragma unroll
  for (int o = 32; o; o >>= 1) v1 += __shfl_down(v1, o, 64);
  __shared__ float s1[BS / 64];
  int lane = threadIdx.x & 63, wid = threadIdx.x >> 6;
  if (lane == 0) s1[wid] = v1;
  __syncthreads();
  if (threadIdx.x == 0) {
    float t1 = 0.f;
#pragma unroll
    for (int k = 0; k < BS / 64; k++) t1 += s1[k];
    *d1 = t1;
  }
}

template <int BS>
__device__ inline void block_reduce2_store(float v1, float v2, float* d1, float* d2) {
#pragma unroll
  for (int o = 32; o; o >>= 1) {
    v1 += __shfl_down(v1, o, 64);
    v2 += __shfl_down(v2, o, 64);
  }
  __shared__ float s1[BS / 64], s2[BS / 64];
  int lane = threadIdx.x & 63, wid = threadIdx.x >> 6;
  if (lane == 0) { s1[wid] = v1; s2[wid] = v2; }
  __syncthreads();
  if (threadIdx.x == 0) {
    float t1 = 0.f, t2 = 0.f;
#pragma unroll
    for (int k = 0; k < BS / 64; k++) { t1 += s1[k]; t2 += s2[k]; }
    *d1 = t1;
    *d2 = t2;
  }
}

// ---- pass A0: LDS histogram (+ optional coalesced WF={w,flux} write) ----
__global__ __launch_bounds__(TPB_A) void hist_wf(
    const int* __restrict__ ei, const float* __restrict__ u_hat,
    const float* __restrict__ fn, const float* __restrict__ fa,
    const float* __restrict__ fd, unsigned* __restrict__ mat,
    float2* __restrict__ wf, int E, int NB, int chunk) {
  __shared__ unsigned cntL[MAXNB];
  for (int i = threadIdx.x; i < NB; i += TPB_A) cntL[i] = 0;
  __syncthreads();
  int blk = blockIdx.x;
  int e0 = blk * chunk, e1 = min(E, e0 + chunk);
  for (int e = e0 + threadIdx.x; e < e1; e += TPB_A) {
    int d = ei[E + e];
    atomicAdd(&cntL[((unsigned)d) >> BSHIFT], 1u);
    if (wf) {
      int s = ei[e];
      float area = fa[e];
      float w = area / fmaxf(fd[e], 1e-8f);
      float ux = 0.5f * (u_hat[3 * s]     + u_hat[3 * d]);
      float uy = 0.5f * (u_hat[3 * s + 1] + u_hat[3 * d + 1]);
      float uz = 0.5f * (u_hat[3 * s + 2] + u_hat[3 * d + 2]);
      float flux = (ux * fn[3 * e] + uy * fn[3 * e + 1] + uz * fn[3 * e + 2]) * area;
      wf[e] = make_float2(w, flux);
    }
  }
  __syncthreads();
  for (int b = threadIdx.x; b < NB; b += TPB_A)
    mat[(size_t)b * NBLK + blk] = cntL[b];
}

// ---- scan (1024 elems / block) ----
__global__ __launch_bounds__(TPB) void scan_blocks(
    const unsigned* __restrict__ cnt, unsigned* __restrict__ offs,
    unsigned* __restrict__ btot, int n) {
  __shared__ unsigned sd[TPB];
  int t = threadIdx.x;
  int base = blockIdx.x * 1024 + t * 4;
  unsigned v0 = 0, v1 = 0, v2 = 0, v3 = 0;
  if (base + 0 < n) v0 = cnt[base + 0];
  if (base + 1 < n) v1 = cnt[base + 1];
  if (base + 2 < n) v2 = cnt[base + 2];
  if (base + 3 < n) v3 = cnt[base + 3];
  unsigned local = v0 + v1 + v2 + v3;
  sd[t] = local;
  __syncthreads();
  for (int o = 1; o < TPB; o <<= 1) {
    unsigned x = (t >= o) ? sd[t - o] : 0u;
    __syncthreads();
    sd[t] += x;
    __syncthreads();
  }
  unsigned excl = sd[t] - local;
  if (base + 0 < n) offs[base + 0] = excl; excl += v0;
  if (base + 1 < n) offs[base + 1] = excl; excl += v1;
  if (base + 2 < n) offs[base + 2] = excl; excl += v2;
  if (base + 3 < n) offs[base + 3] = excl;
  if (t == TPB - 1) btot[blockIdx.x] = sd[TPB - 1];
}

__global__ __launch_bounds__(512) void scan_totals(unsigned* __restrict__ btot, int nb) {
  __shared__ unsigned sd[512];
  int t = threadIdx.x;
  unsigned v = (t < nb) ? btot[t] : 0u;
  sd[t] = v;
  __syncthreads();
  for (int o = 1; o < 512; o <<= 1) {
    unsigned x = (t >= o) ? sd[t - o] : 0u;
    __syncthreads();
    sd[t] += x;
    __syncthreads();
  }
  if (t < nb) btot[t] = sd[t] - v;  // exclusive
}

__global__ __launch_bounds__(TPB) void scan_add(
    unsigned* __restrict__ offs, const unsigned* __restrict__ btot,
    int n, unsigned total) {
  int i = blockIdx.x * TPB + threadIdx.x;
  if (i < n) offs[i] += btot[i >> 10];
  if (i == 0) offs[n] = total;
}

// ---- pass A1: place edges as 16-B {hi, w, flux, eid} ----
__global__ __launch_bounds__(TPB_A) void bucket_place(
    const int* __restrict__ ei, const float* __restrict__ u_hat,
    const float* __restrict__ fn, const float* __restrict__ fa,
    const float* __restrict__ fd, const float2* __restrict__ wf,
    const unsigned* __restrict__ offs, uint4* __restrict__ A16,
    int E, int NB, int chunk) {
  __shared__ unsigned cntL[MAXNB];
  __shared__ unsigned offL[MAXNB];
  int blk = blockIdx.x;
  for (int i = threadIdx.x; i < NB; i += TPB_A) {
    cntL[i] = 0;
    offL[i] = offs[(size_t)i * NBLK + blk];
  }
  __syncthreads();
  int e0 = blk * chunk, e1 = min(E, e0 + chunk);
  for (int e = e0 + threadIdx.x; e < e1; e += TPB_A) {
    int s = ei[e], d = ei[E + e];
    float w, flux;
    if (wf) {
      float2 v = wf[e];
      w = v.x; flux = v.y;
    } else {
      float area = fa[e];
      w = area / fmaxf(fd[e], 1e-8f);
      float ux = 0.5f * (u_hat[3 * s]     + u_hat[3 * d]);
      float uy = 0.5f * (u_hat[3 * s + 1] + u_hat[3 * d + 1]);
      float uz = 0.5f * (u_hat[3 * s + 2] + u_hat[3 * d + 2]);
      flux = (ux * fn[3 * e] + uy * fn[3 * e + 1] + uz * fn[3 * e + 2]) * area;
    }
    unsigned b = ((unsigned)d) >> BSHIFT;
    unsigned dl = ((unsigned)d) & (BSIZE - 1u);
    unsigned r = atomicAdd(&cntL[b], 1u);
    unsigned pos = offL[b] + r;
    unsigned hi = (dl << 19) | (unsigned)s;
    A16[(size_t)pos] = make_uint4(hi, __float_as_uint(w),
                                  __float_as_uint(flux), (unsigned)e);
  }
}

// ---- CG setup + within-bucket counting sort to CSR ----
// pass1: LDS histogram (cnt) + wsum/flux accumulate.
// scan:  Hillis-Steele 1024-bin exclusive prefix -> row bases.
// pass2: re-read A16, place A8[pos] = {src lo32, w hi32} sorted by dst.
__global__ __launch_bounds__(TPB_B) void node_setup(
    const uint4* __restrict__ A16, ull* __restrict__ A8,
    unsigned* __restrict__ rowptr,
    const unsigned* __restrict__ offs, const float* __restrict__ cv,
    float* __restrict__ diag, float* __restrict__ minv,
    float* __restrict__ r, float* __restrict__ z, float* __restrict__ phi,
    float* __restrict__ rz_part, float* __restrict__ rr_part,
    int N, int NB, int E) {
  __shared__ unsigned cntS[TPB_B];
  __shared__ unsigned scanS[TPB_B];
  __shared__ float wacc[TPB_B], facc[TPB_B];
  int b = blockIdx.x;
  int t = threadIdx.x;
  float rzv = 0.f, rrv = 0.f;
  if (b < NB) {
    cntS[t] = 0; wacc[t] = 0.f; facc[t] = 0.f;
    __syncthreads();
    unsigned jb = offs[(size_t)b * NBLK], je = offs[(size_t)(b + 1) * NBLK];
    const ull* q = (const ull*)A16;
    for (unsigned j = jb + t; j < je; j += TPB_B) {
      ull a = __builtin_nontemporal_load(&q[(size_t)2 * j]);      // {hi, w}
      ull c = __builtin_nontemporal_load(&q[(size_t)2 * j + 1]);  // {flux, eid}
      unsigned hi = (unsigned)a;
      unsigned dl = hi >> 19;
      atomicAdd(&cntS[dl], 1u);
      atomicAdd(&wacc[dl], __uint_as_float((unsigned)(a >> 32)));
      atomicAdd(&facc[dl], __uint_as_float((unsigned)c));
    }
    __syncthreads();
    // exclusive scan of cnt -> row bases
    scanS[t] = cntS[t];
    __syncthreads();
    for (int o = 1; o < TPB_B; o <<= 1) {
      unsigned x = (t >= o) ? scanS[t - o] : 0u;
      __syncthreads();
      scanS[t] += x;
      __syncthreads();
    }
    unsigned baseE = scanS[t] - cntS[t];
    __syncthreads();
    scanS[t] = baseE;   // scanS = row base per local node
    cntS[t] = 0;        // reuse as placement counter
    __syncthreads();
    if (A8 && rowptr) {
      for (unsigned j = jb + t; j < je; j += TPB_B) {
        ull a = __builtin_nontemporal_load(&q[(size_t)2 * j]);    // {hi, w}
        unsigned hi = (unsigned)a;
        unsigned dl = hi >> 19, src = hi & 0x7FFFFu;
        unsigned rk = atomicAdd(&cntS[dl], 1u);
        unsigned pos = jb + scanS[dl] + rk;
        A8[(size_t)pos] = (a & 0xFFFFFFFF00000000ull) | (ull)src;  // {src, w}
      }
    }
    int node = (b << BSHIFT) + t;
    if (node < N) {
      float wsum = wacc[t];
      float vol = fmaxf(cv[node], 1e-12f);
      float bval = facc[t] / vol;
      float mi = 1.0f / fmaxf(wsum, 1e-8f);
      diag[node] = wsum;
      minv[node] = mi;
      r[node] = bval;
      float zi = mi * bval;
      z[node] = zi;
      phi[node] = 0.f;
      if (rowptr) rowptr[node] = jb + baseE;
      rzv = bval * zi;
      rrv = bval * bval;
    }
    if (rowptr && b == NB - 1 && t == 0) rowptr[N] = (unsigned)E;
  }
  block_reduce2_store<TPB_B>(rzv, rrv, &rz_part[blockIdx.x], &rr_part[blockIdx.x]);
}

// ---- matvec on z: CSR register-accumulate (no LDS atomics);
// p/ap via recurrence (dense). Fallback: R10 LDS-atomic path on A16.
__global__ __launch_bounds__(TPB_B, 8) void matvec_az(
    const float* __restrict__ z, const float* __restrict__ diag,
    const unsigned* __restrict__ offs, const ull* __restrict__ A8,
    const unsigned* __restrict__ rowptr, const uint4* __restrict__ A16,
    const float* __restrict__ p_old, float* __restrict__ p_new,
    const float* __restrict__ ap_old, float* __restrict__ ap_new,
    float* __restrict__ pap_part,
    const float* __restrict__ rzJ_part, const float* __restrict__ rzJm1_part,
    const float* __restrict__ rrJ_part, int N, int first) {
  int b = blockIdx.x, t = threadIdx.x;
  float beta = 0.f;
  bool act = true;
  if (!first) {
    Sum3 s = block_sum3n_bcast<TPB_B>(rzJ_part, KB, rzJm1_part, KB, rrJ_part, KB);
    act = (s.c >= TOL2);
    beta = s.a / (s.b + 1e-12f);
  }
  int node = (b << BSHIFT) + t;
  float accv = 0.f;
  if (A8 && rowptr) {
    if (node < N) {
      unsigned r0 = rowptr[node], r1 = rowptr[node + 1];
      unsigned j = r0;
      for (; j + 1 < r1; j += 2) {
        ull v0 = __builtin_nontemporal_load(&A8[(size_t)j]);
        ull v1 = __builtin_nontemporal_load(&A8[(size_t)j + 1]);
        float z0 = z[(unsigned)v0];
        float z1 = z[(unsigned)v1];
        accv = fmaf(__uint_as_float((unsigned)(v0 >> 32)), z0, accv);
        accv = fmaf(__uint_as_float((unsigned)(v1 >> 32)), z1, accv);
      }
      if (j < r1) {
        ull v0 = __builtin_nontemporal_load(&A8[(size_t)j]);
        accv = fmaf(__uint_as_float((unsigned)(v0 >> 32)), z[(unsigned)v0], accv);
      }
    }
  } else {
    __shared__ float accS[TPB_B];
    accS[t] = 0.f;
    __syncthreads();
    unsigned jb = offs[(size_t)b * NBLK], je = offs[(size_t)(b + 1) * NBLK];
    const ull* q = (const ull*)A16;
    for (unsigned j = jb + t; j < je; j += TPB_B) {
      ull v = __builtin_nontemporal_load(&q[(size_t)2 * j]);
      unsigned hi = (unsigned)v;
      float w = __uint_as_float((unsigned)(v >> 32));
      atomicAdd(&accS[hi >> 19], w * z[hi & 0x7FFFFu]);
    }
    __syncthreads();
    accv = accS[t];
  }
  float contrib = 0.f;
  if (node < N) {
    float zi = z[node];
    float az = diag[node] * zi - accv;
    float pn, apn;
    if (first)    { pn = zi;                          apn = az; }
    else if (act) { pn = fmaf(beta, p_old[node], zi); apn = fmaf(beta, ap_old[node], az); }
    else          { pn = p_old[node];                 apn = ap_old[node]; }
    p_new[node] = pn;
    ap_new[node] = apn;
    contrib = pn * apn;
  }
  block_reduce1_store<TPB_B>(contrib, &pap_part[b]);
}

// ---- gated phi/r update; writes z = minv*r; emits rz/rr partials ----
__global__ __launch_bounds__(TPB) void cg_update(
    float* __restrict__ phi, float* __restrict__ r, const float* __restrict__ p,
    const float* __restrict__ ap, const float* __restrict__ minv,
    float* __restrict__ z,
    const float* __restrict__ pap_it, const float* __restrict__ rz_it,
    const float* __restrict__ rr_it, float* __restrict__ rz_next,
    float* __restrict__ rr_next, int N, int NB) {
  Sum3 s = block_sum3n_bcast<TPB>(pap_it, NB, rz_it, KB, rr_it, KB);
  bool act = (s.c >= TOL2);
  float alpha = s.b / (s.a + 1e-12f);
  float rzacc = 0.f, rracc = 0.f;
  for (int i = blockIdx.x * TPB + threadIdx.x; i < N; i += KB * TPB) {
    float ri = r[i];
    if (act) {
      phi[i] += alpha * p[i];
      ri -= alpha * ap[i];
      r[i] = ri;
    }
    float zi = minv[i] * ri;
    z[i] = zi;
    rzacc += ri * zi;
    rracc += ri * ri;
  }
  block_reduce2_store<TPB>(rzacc, rracc, &rz_next[blockIdx.x], &rr_next[blockIdx.x]);
}

// ---- pressure correction + output: per-bucket LDS grad accumulate ----
__global__ __launch_bounds__(TPB_B) void finalize(
    const float* __restrict__ u_hat, const float* __restrict__ cv,
    const float* __restrict__ phi, const unsigned* __restrict__ offs,
    const uint4* __restrict__ A16, const float* __restrict__ fn,
    float* __restrict__ out, int N, int NB) {
  __shared__ float gxa[TPB_B], gya[TPB_B], gza[TPB_B];
  int b = blockIdx.x;
  if (b >= NB) return;
  gxa[threadIdx.x] = 0.f;
  gya[threadIdx.x] = 0.f;
  gza[threadIdx.x] = 0.f;
  __syncthreads();
  unsigned jb = offs[(size_t)b * NBLK], je = offs[(size_t)(b + 1) * NBLK];
  const ull* q = (const ull*)A16;
  for (unsigned j = jb + threadIdx.x; j < je; j += TPB_B) {
    ull a = __builtin_nontemporal_load(&q[(size_t)2 * j]);      // {hi, w}
    ull bq = __builtin_nontemporal_load(&q[(size_t)2 * j + 1]); // {flux, eid}
    unsigned hi = (unsigned)a;
    float w = __uint_as_float((unsigned)(a >> 32));
    int e = (int)(unsigned)(bq >> 32);
    float t = w * phi[hi & 0x7FFFFu];
    int dl = hi >> 19;
    atomicAdd(&gxa[dl], t * fn[3 * e]);
    atomicAdd(&gya[dl], t * fn[3 * e + 1]);
    atomicAdd(&gza[dl], t * fn[3 * e + 2]);
  }
  __syncthreads();
  int node = (b << BSHIFT) + threadIdx.x;
  if (node < N) {
    float iv = 1.0f / fmaxf(cv[node], 1e-12f);
    out[3 * node]     = u_hat[3 * node]     - gxa[threadIdx.x] * iv;
    out[3 * node + 1] = u_hat[3 * node + 1] - gya[threadIdx.x] * iv;
    out[3 * node + 2] = u_hat[3 * node + 2] - gza[threadIdx.x] * iv;
    out[3 * N + node] = phi[node];
  }
}

extern "C" void kernel_launch(void* const* d_in, const int* in_sizes, int n_in,
                              void* d_out, int out_size, void* d_ws, size_t ws_size,
                              hipStream_t stream) {
  const float* u_hat = (const float*)d_in[0];
  const int*   ei    = (const int*)d_in[1];
  const float* fn    = (const float*)d_in[2];
  const float* fa    = (const float*)d_in[3];
  const float* fd    = (const float*)d_in[4];
  const float* cv    = (const float*)d_in[5];
  float* out = (float*)d_out;

  const int N = in_sizes[0] / 3;   // 500,000
  const int E = in_sizes[1] / 2;   // 8,000,000
  const int NB = (N + BSIZE - 1) >> BSHIFT;  // coarse buckets (489)
  const int NS = NB * NBLK;        // scan length (125,184)
  const int chunk = (E + NBLK - 1) / NBLK;

  // ---- workspace bump allocator (256B aligned) ----
  char* base = (char*)d_ws;
  size_t off = 0;
  auto alloc = [&](size_t bytes) -> void* {
    void* ptr = base + off;
    off = (off + bytes + 255) & ~size_t(255);
    return ptr;
  };
  unsigned* mat   = (unsigned*)alloc((size_t)NS * 4);
  unsigned* offs  = (unsigned*)alloc((size_t)(NS + 1) * 4);
  unsigned* btot  = (unsigned*)alloc(512 * 4);
  float*    diag  = (float*)alloc((size_t)N * 4);
  float*    minv  = (float*)alloc((size_t)N * 4);
  float*    phi   = (float*)alloc((size_t)N * 4);
  float*    rvec  = (float*)alloc((size_t)N * 4);
  float*    zvec  = (float*)alloc((size_t)N * 4);
  float*    pA    = (float*)alloc((size_t)N * 4);
  float*    pB    = (float*)alloc((size_t)N * 4);
  float*    apA   = (float*)alloc((size_t)N * 4);
  float*    apB   = (float*)alloc((size_t)N * 4);
  unsigned* rowptr = (unsigned*)alloc((size_t)(N + 1) * 4);
  float*    rzrr  = (float*)alloc((size_t)(2 * (CG_ITERS + 1)) * KB * 4);
  float*    papp  = (float*)alloc((size_t)CG_ITERS * KB * 4);
  uint4*    A16   = (uint4*)alloc((size_t)E * 16);      // base ≈ 150 MB
  ull* A8 = nullptr;                                    // tier 1: +64 MB (CSR)
  if (off + (size_t)E * 8 + 256 <= ws_size) A8 = (ull*)alloc((size_t)E * 8);
  float2* WF = nullptr;                                 // tier 2: +64 MB
  if (off + (size_t)E * 8 + 256 <= ws_size) WF = (float2*)alloc((size_t)E * 8);
  (void)n_in; (void)out_size;

  auto rz_part = [&](int it) { return rzrr + (size_t)(2 * it) * KB; };
  auto rr_part = [&](int it) { return rzrr + (size_t)(2 * it + 1) * KB; };
  auto pap_part = [&](int it) { return papp + (size_t)it * KB; };

  const int nbScan = (NS + 1023) / 1024;          // 123 <= 512
  const int gridScanAdd = (NS + TPB - 1) / TPB;

  hist_wf<<<NBLK, TPB_A, 0, stream>>>(ei, u_hat, fn, fa, fd, mat, WF,
                                      E, NB, chunk);

  scan_blocks<<<nbScan, TPB, 0, stream>>>(mat, offs, btot, NS);
  scan_totals<<<1, 512, 0, stream>>>(btot, nbScan);
  scan_add<<<gridScanAdd, TPB, 0, stream>>>(offs, btot, NS, (unsigned)E);

  bucket_place<<<NBLK, TPB_A, 0, stream>>>(ei, u_hat, fn, fa, fd, WF, offs,
                                           A16, E, NB, chunk);

  node_setup<<<KB, TPB_B, 0, stream>>>(A16, A8, rowptr, offs, cv, diag, minv,
                                       rvec, zvec, phi,
                                       rz_part(0), rr_part(0), N, NB, E);

  float* pbuf[2]  = {pA, pB};
  float* apbuf[2] = {apA, apB};
  for (int it = 0; it < CG_ITERS; it++) {
    int ni = it & 1;                 // new buffer index
    float* pn  = pbuf[ni];
    float* apn = apbuf[ni];
    const float* po  = pbuf[1 - ni];
    const float* apo = apbuf[1 - ni];
    int first = (it == 0) ? 1 : 0;
    matvec_az<<<NB, TPB_B, 0, stream>>>(zvec, diag, offs, A8, rowptr, A16,
                                        po, pn, apo, apn, pap_part(it),
                                        rz_part(it), rz_part(it > 0 ? it - 1 : 0),
                                        rr_part(it), N, first);
    cg_update<<<KB, TPB, 0, stream>>>(phi, rvec, pn, apn, minv, zvec,
                                      pap_part(it), rz_part(it), rr_part(it),
                                      rz_part(it + 1), rr_part(it + 1), N, NB);
  }

  finalize<<<NB, TPB_B, 0, stream>>>(u_hat, cv, phi, offs, A16,
                                     fn, out, N, NB);
}

// Round 7
// 2108.335 us; speedup vs baseline: 4.7117x; 1.5916x over previous
//
#include <hip/hip_runtime.h>

// PressureProjection on MI355X — round 13.
// R12 post-mortem: scalar CSR row-walk matvec is the classic SpMV mistake
// (uncoalesced per-lane rows, row-length divergence, nt-loads defeating line
// reuse) -> CG 72->129us/iter, total 3355. Also: 8M LDS atomics = ~2us/CU,
// NOT the matvec bottleneck (R12 premise was arithmetically wrong).
// R10 matvec 45us = payload stream 11us + z-gather L2 transactions + POOR
// GRID FILL (489 blocks = 1.9/CU, 2-round imbalance) + short dependent loop.
// R13 = R10 structure (2164us proven) with:
//  * BSHIFT 9: 977 buckets x 512 thr -> 3.8 blocks/CU single-round fill
//    (4 blk/CU x 8 waves = full occupancy) for matvec/node_setup/finalize.
//  * matvec edge loop: paired 16-B nt loads (2 entries/thread/iter), two
//    independent gather chains -> MLP; LDS-atomic accumulate (proven).
//  * no sort, no rowptr, no CSR.
// Predicted: node_setup ~150, matvec ~30 (occupancy up), total ~1900.
// Falsifier: matvec >=40us at full occupancy => z-gather transaction-bound.

#define TPB 256
#define TPB_A 1024
#define TPB_B 512        // bucket kernels: 1 thread per node in bucket
#define KB 2048          // grid for dense kernels & partial arrays
#define NBLK 256         // chunks for bucket sort
#define BSHIFT 9         // bucket = dst >> 9 (512 nodes per bucket)
#define BSIZE 512
#define MAXNB 1024       // max coarse buckets (N <= 524288)
#define CG_ITERS 20
#define TOL2 1e-8f       // (CG_TOL=1e-4)^2

typedef unsigned long long ull;
typedef ull v2u __attribute__((ext_vector_type(2)));

struct Sum3 { float a, b, c; };

// block-wide sums of three arrays (independent lengths), broadcast
template <int BS>
__device__ inline Sum3 block_sum3n_bcast(const float* __restrict__ A, int nA,
                                         const float* __restrict__ B, int nB,
                                         const float* __restrict__ C, int nC) {
  float va = 0.f, vb = 0.f, vc = 0.f;
  for (int k = threadIdx.x; k < nA; k += BS) va += A[k];
  for (int k = threadIdx.x; k < nB; k += BS) vb += B[k];
  for (int k = threadIdx.x; k < nC; k += BS) vc += C[k];
#pragma unroll
  for (int o = 32; o; o >>= 1) {
    va += __shfl_down(va, o, 64);
    vb += __shfl_down(vb, o, 64);
    vc += __shfl_down(vc, o, 64);
  }
  __shared__ float sa[BS / 64], sb[BS / 64], sc[BS / 64], bc[3];
  int lane = threadIdx.x & 63, wid = threadIdx.x >> 6;
  if (lane == 0) { sa[wid] = va; sb[wid] = vb; sc[wid] = vc; }
  __syncthreads();
  if (threadIdx.x == 0) {
    float ta = 0.f, tb = 0.f, tc = 0.f;
#pragma unroll
    for (int k = 0; k < BS / 64; k++) { ta += sa[k]; tb += sb[k]; tc += sc[k]; }
    bc[0] = ta; bc[1] = tb; bc[2] = tc;
  }
  __syncthreads();
  Sum3 r{bc[0], bc[1], bc[2]};
  __syncthreads();
  return r;
}

template <int BS>
__device__ inline void block_reduce1_store(float v1, float* d1) {
#pragma unroll
  for (int o = 32; o; o >>= 1) v1 += __shfl_down(v1, o, 64);
  __shared__ float s1[BS / 64];
  int lane = threadIdx.x & 63, wid = threadIdx.x >> 6;
  if (lane == 0) s1[wid] = v1;
  __syncthreads();
  if (threadIdx.x == 0) {
    float t1 = 0.f;
#pragma unroll
    for (int k = 0; k < BS / 64; k++) t1 += s1[k];
    *d1 = t1;
  }
}

template <int BS>
__device__ inline void block_reduce2_store(float v1, float v2, float* d1, float* d2) {
#pragma unroll
  for (int o = 32; o; o >>= 1) {
    v1 += __shfl_down(v1, o, 64);
    v2 += __shfl_down(v2, o, 64);
  }
  __shared__ float s1[BS / 64], s2[BS / 64];
  int lane = threadIdx.x & 63, wid = threadIdx.x >> 6;
  if (lane == 0) { s1[wid] = v1; s2[wid] = v2; }
  __syncthreads();
  if (threadIdx.x == 0) {
    float t1 = 0.f, t2 = 0.f;
#pragma unroll
    for (int k = 0; k < BS / 64; k++) { t1 += s1[k]; t2 += s2[k]; }
    *d1 = t1;
    *d2 = t2;
  }
}

// ---- pass A0: LDS histogram (+ optional coalesced WF={w,flux} write) ----
__global__ __launch_bounds__(TPB_A) void hist_wf(
    const int* __restrict__ ei, const float* __restrict__ u_hat,
    const float* __restrict__ fn, const float* __restrict__ fa,
    const float* __restrict__ fd, unsigned* __restrict__ mat,
    float2* __restrict__ wf, int E, int NB, int chunk) {
  __shared__ unsigned cntL[MAXNB];
  for (int i = threadIdx.x; i < NB; i += TPB_A) cntL[i] = 0;
  __syncthreads();
  int blk = blockIdx.x;
  int e0 = blk * chunk, e1 = min(E, e0 + chunk);
  for (int e = e0 + threadIdx.x; e < e1; e += TPB_A) {
    int d = ei[E + e];
    atomicAdd(&cntL[((unsigned)d) >> BSHIFT], 1u);
    if (wf) {
      int s = ei[e];
      float area = fa[e];
      float w = area / fmaxf(fd[e], 1e-8f);
      float ux = 0.5f * (u_hat[3 * s]     + u_hat[3 * d]);
      float uy = 0.5f * (u_hat[3 * s + 1] + u_hat[3 * d + 1]);
      float uz = 0.5f * (u_hat[3 * s + 2] + u_hat[3 * d + 2]);
      float flux = (ux * fn[3 * e] + uy * fn[3 * e + 1] + uz * fn[3 * e + 2]) * area;
      wf[e] = make_float2(w, flux);
    }
  }
  __syncthreads();
  for (int b = threadIdx.x; b < NB; b += TPB_A)
    mat[(size_t)b * NBLK + blk] = cntL[b];
}

// ---- scan (1024 elems / block) ----
__global__ __launch_bounds__(TPB) void scan_blocks(
    const unsigned* __restrict__ cnt, unsigned* __restrict__ offs,
    unsigned* __restrict__ btot, int n) {
  __shared__ unsigned sd[TPB];
  int t = threadIdx.x;
  int base = blockIdx.x * 1024 + t * 4;
  unsigned v0 = 0, v1 = 0, v2 = 0, v3 = 0;
  if (base + 0 < n) v0 = cnt[base + 0];
  if (base + 1 < n) v1 = cnt[base + 1];
  if (base + 2 < n) v2 = cnt[base + 2];
  if (base + 3 < n) v3 = cnt[base + 3];
  unsigned local = v0 + v1 + v2 + v3;
  sd[t] = local;
  __syncthreads();
  for (int o = 1; o < TPB; o <<= 1) {
    unsigned x = (t >= o) ? sd[t - o] : 0u;
    __syncthreads();
    sd[t] += x;
    __syncthreads();
  }
  unsigned excl = sd[t] - local;
  if (base + 0 < n) offs[base + 0] = excl; excl += v0;
  if (base + 1 < n) offs[base + 1] = excl; excl += v1;
  if (base + 2 < n) offs[base + 2] = excl; excl += v2;
  if (base + 3 < n) offs[base + 3] = excl;
  if (t == TPB - 1) btot[blockIdx.x] = sd[TPB - 1];
}

__global__ __launch_bounds__(512) void scan_totals(unsigned* __restrict__ btot, int nb) {
  __shared__ unsigned sd[512];
  int t = threadIdx.x;
  unsigned v = (t < nb) ? btot[t] : 0u;
  sd[t] = v;
  __syncthreads();
  for (int o = 1; o < 512; o <<= 1) {
    unsigned x = (t >= o) ? sd[t - o] : 0u;
    __syncthreads();
    sd[t] += x;
    __syncthreads();
  }
  if (t < nb) btot[t] = sd[t] - v;  // exclusive
}

__global__ __launch_bounds__(TPB) void scan_add(
    unsigned* __restrict__ offs, const unsigned* __restrict__ btot,
    int n, unsigned total) {
  int i = blockIdx.x * TPB + threadIdx.x;
  if (i < n) offs[i] += btot[i >> 10];
  if (i == 0) offs[n] = total;
}

// ---- pass A1: place edges as 16-B {hi, w, flux, eid} ----
__global__ __launch_bounds__(TPB_A) void bucket_place(
    const int* __restrict__ ei, const float* __restrict__ u_hat,
    const float* __restrict__ fn, const float* __restrict__ fa,
    const float* __restrict__ fd, const float2* __restrict__ wf,
    const unsigned* __restrict__ offs, uint4* __restrict__ A16,
    int E, int NB, int chunk) {
  __shared__ unsigned cntL[MAXNB];
  __shared__ unsigned offL[MAXNB];
  int blk = blockIdx.x;
  for (int i = threadIdx.x; i < NB; i += TPB_A) {
    cntL[i] = 0;
    offL[i] = offs[(size_t)i * NBLK + blk];
  }
  __syncthreads();
  int e0 = blk * chunk, e1 = min(E, e0 + chunk);
  for (int e = e0 + threadIdx.x; e < e1; e += TPB_A) {
    int s = ei[e], d = ei[E + e];
    float w, flux;
    if (wf) {
      float2 v = wf[e];
      w = v.x; flux = v.y;
    } else {
      float area = fa[e];
      w = area / fmaxf(fd[e], 1e-8f);
      float ux = 0.5f * (u_hat[3 * s]     + u_hat[3 * d]);
      float uy = 0.5f * (u_hat[3 * s + 1] + u_hat[3 * d + 1]);
      float uz = 0.5f * (u_hat[3 * s + 2] + u_hat[3 * d + 2]);
      flux = (ux * fn[3 * e] + uy * fn[3 * e + 1] + uz * fn[3 * e + 2]) * area;
    }
    unsigned b = ((unsigned)d) >> BSHIFT;
    unsigned dl = ((unsigned)d) & (BSIZE - 1u);
    unsigned r = atomicAdd(&cntL[b], 1u);
    unsigned pos = offL[b] + r;
    unsigned hi = (dl << 19) | (unsigned)s;
    A16[(size_t)pos] = make_uint4(hi, __float_as_uint(w),
                                  __float_as_uint(flux), (unsigned)e);
  }
}

// ---- CG setup: per-bucket LDS sums of w and flux; splits hot A8 stream ----
__global__ __launch_bounds__(TPB_B) void node_setup(
    const uint4* __restrict__ A16, ull* __restrict__ A8,
    const unsigned* __restrict__ offs, const float* __restrict__ cv,
    float* __restrict__ diag, float* __restrict__ minv,
    float* __restrict__ r, float* __restrict__ z, float* __restrict__ phi,
    float* __restrict__ rz_part, float* __restrict__ rr_part, int N, int NB) {
  __shared__ float wacc[TPB_B], facc[TPB_B];
  int b = blockIdx.x;
  float rzv = 0.f, rrv = 0.f;
  if (b < NB) {
    wacc[threadIdx.x] = 0.f;
    facc[threadIdx.x] = 0.f;
    __syncthreads();
    unsigned jb = offs[(size_t)b * NBLK], je = offs[(size_t)(b + 1) * NBLK];
    const v2u* Q = (const v2u*)A16;
    for (unsigned j = jb + threadIdx.x; j < je; j += TPB_B) {
      v2u a = __builtin_nontemporal_load(&Q[(size_t)j]);  // {hi,w | flux,eid}
      unsigned hi = (unsigned)a[0];
      float w = __uint_as_float((unsigned)(a[0] >> 32));
      float flux = __uint_as_float((unsigned)a[1]);
      atomicAdd(&wacc[hi >> 19], w);
      atomicAdd(&facc[hi >> 19], flux);
      if (A8) A8[(size_t)j] = a[0];  // sequential 8-B hot stream {hi,w}
    }
    __syncthreads();
    int node = (b << BSHIFT) + threadIdx.x;
    if (node < N) {
      float wsum = wacc[threadIdx.x];
      float vol = fmaxf(cv[node], 1e-12f);
      float bval = facc[threadIdx.x] / vol;
      float mi = 1.0f / fmaxf(wsum, 1e-8f);
      diag[node] = wsum;
      minv[node] = mi;
      r[node] = bval;
      float zi = mi * bval;
      z[node] = zi;
      phi[node] = 0.f;
      rzv = bval * zi;
      rrv = bval * bval;
    }
  }
  block_reduce2_store<TPB_B>(rzv, rrv, &rz_part[blockIdx.x], &rr_part[blockIdx.x]);
}

// ---- matvec on z: bucketed LDS-atomic accumulate, paired 16-B nt loads;
// p/ap via recurrence (dense). Fallback: A16 scalar path.
__global__ __launch_bounds__(TPB_B) void matvec_az(
    const float* __restrict__ z, const float* __restrict__ diag,
    const unsigned* __restrict__ offs, const ull* __restrict__ A8,
    const uint4* __restrict__ A16,
    const float* __restrict__ p_old, float* __restrict__ p_new,
    const float* __restrict__ ap_old, float* __restrict__ ap_new,
    float* __restrict__ pap_part,
    const float* __restrict__ rzJ_part, const float* __restrict__ rzJm1_part,
    const float* __restrict__ rrJ_part, int N, int first) {
  __shared__ float acc[TPB_B];
  int b = blockIdx.x, t = threadIdx.x;
  acc[t] = 0.f;
  __syncthreads();
  unsigned jb = offs[(size_t)b * NBLK], je = offs[(size_t)(b + 1) * NBLK];
  if (A8) {
    // scalar head so the paired loop starts 16-B aligned
    unsigned jv = jb;
    if (jb & 1u) {
      if (t == 0 && jb < je) {
        ull v = A8[(size_t)jb];
        unsigned h = (unsigned)v;
        atomicAdd(&acc[h >> 19], __uint_as_float((unsigned)(v >> 32)) * z[h & 0x7FFFFu]);
      }
      jv = jb + 1;
    }
    if (jv > je) jv = je;
    unsigned npairs = (je - jv) >> 1;
    const v2u* P = (const v2u*)(A8 + jv);
    for (unsigned p = t; p < npairs; p += TPB_B) {
      v2u v = __builtin_nontemporal_load(&P[(size_t)p]);
      unsigned h0 = (unsigned)v[0], h1 = (unsigned)v[1];
      float z0 = z[h0 & 0x7FFFFu];
      float z1 = z[h1 & 0x7FFFFu];
      atomicAdd(&acc[h0 >> 19], __uint_as_float((unsigned)(v[0] >> 32)) * z0);
      atomicAdd(&acc[h1 >> 19], __uint_as_float((unsigned)(v[1] >> 32)) * z1);
    }
    if (((je - jv) & 1u) && t == 0) {
      ull v = A8[(size_t)(je - 1)];
      unsigned h = (unsigned)v;
      atomicAdd(&acc[h >> 19], __uint_as_float((unsigned)(v >> 32)) * z[h & 0x7FFFFu]);
    }
  } else {
    const v2u* Q = (const v2u*)A16;
    for (unsigned j = jb + t; j < je; j += TPB_B) {
      v2u a = __builtin_nontemporal_load(&Q[(size_t)j]);
      unsigned hi = (unsigned)a[0];
      float w = __uint_as_float((unsigned)(a[0] >> 32));
      atomicAdd(&acc[hi >> 19], w * z[hi & 0x7FFFFu]);
    }
  }
  __syncthreads();
  float beta = 0.f;
  bool act = true;
  if (!first) {
    Sum3 s = block_sum3n_bcast<TPB_B>(rzJ_part, KB, rzJm1_part, KB, rrJ_part, KB);
    act = (s.c >= TOL2);
    beta = s.a / (s.b + 1e-12f);
  }
  float contrib = 0.f;
  int node = (b << BSHIFT) + t;
  if (node < N) {
    float zi = z[node];
    float az = diag[node] * zi - acc[t];
    float pn, apn;
    if (first)    { pn = zi;                          apn = az; }
    else if (act) { pn = fmaf(beta, p_old[node], zi); apn = fmaf(beta, ap_old[node], az); }
    else          { pn = p_old[node];                 apn = ap_old[node]; }
    p_new[node] = pn;
    ap_new[node] = apn;
    contrib = pn * apn;
  }
  block_reduce1_store<TPB_B>(contrib, &pap_part[b]);
}

// ---- gated phi/r update; writes z = minv*r; emits rz/rr partials ----
__global__ __launch_bounds__(TPB) void cg_update(
    float* __restrict__ phi, float* __restrict__ r, const float* __restrict__ p,
    const float* __restrict__ ap, const float* __restrict__ minv,
    float* __restrict__ z,
    const float* __restrict__ pap_it, const float* __restrict__ rz_it,
    const float* __restrict__ rr_it, float* __restrict__ rz_next,
    float* __restrict__ rr_next, int N, int NB) {
  Sum3 s = block_sum3n_bcast<TPB>(pap_it, NB, rz_it, KB, rr_it, KB);
  bool act = (s.c >= TOL2);
  float alpha = s.b / (s.a + 1e-12f);
  float rzacc = 0.f, rracc = 0.f;
  for (int i = blockIdx.x * TPB + threadIdx.x; i < N; i += KB * TPB) {
    float ri = r[i];
    if (act) {
      phi[i] += alpha * p[i];
      ri -= alpha * ap[i];
      r[i] = ri;
    }
    float zi = minv[i] * ri;
    z[i] = zi;
    rzacc += ri * zi;
    rracc += ri * ri;
  }
  block_reduce2_store<TPB>(rzacc, rracc, &rz_next[blockIdx.x], &rr_next[blockIdx.x]);
}

// ---- pressure correction + output: per-bucket LDS grad accumulate ----
__global__ __launch_bounds__(TPB_B) void finalize(
    const float* __restrict__ u_hat, const float* __restrict__ cv,
    const float* __restrict__ phi, const unsigned* __restrict__ offs,
    const uint4* __restrict__ A16, const float* __restrict__ fn,
    float* __restrict__ out, int N, int NB) {
  __shared__ float gxa[TPB_B], gya[TPB_B], gza[TPB_B];
  int b = blockIdx.x;
  if (b >= NB) return;
  gxa[threadIdx.x] = 0.f;
  gya[threadIdx.x] = 0.f;
  gza[threadIdx.x] = 0.f;
  __syncthreads();
  unsigned jb = offs[(size_t)b * NBLK], je = offs[(size_t)(b + 1) * NBLK];
  const v2u* Q = (const v2u*)A16;
  for (unsigned j = jb + threadIdx.x; j < je; j += TPB_B) {
    v2u a = __builtin_nontemporal_load(&Q[(size_t)j]);  // {hi,w | flux,eid}
    unsigned hi = (unsigned)a[0];
    float w = __uint_as_float((unsigned)(a[0] >> 32));
    int e = (int)(unsigned)(a[1] >> 32);
    float t = w * phi[hi & 0x7FFFFu];
    int dl = hi >> 19;
    atomicAdd(&gxa[dl], t * fn[3 * e]);
    atomicAdd(&gya[dl], t * fn[3 * e + 1]);
    atomicAdd(&gza[dl], t * fn[3 * e + 2]);
  }
  __syncthreads();
  int node = (b << BSHIFT) + threadIdx.x;
  if (node < N) {
    float iv = 1.0f / fmaxf(cv[node], 1e-12f);
    out[3 * node]     = u_hat[3 * node]     - gxa[threadIdx.x] * iv;
    out[3 * node + 1] = u_hat[3 * node + 1] - gya[threadIdx.x] * iv;
    out[3 * node + 2] = u_hat[3 * node + 2] - gza[threadIdx.x] * iv;
    out[3 * N + node] = phi[node];
  }
}

extern "C" void kernel_launch(void* const* d_in, const int* in_sizes, int n_in,
                              void* d_out, int out_size, void* d_ws, size_t ws_size,
                              hipStream_t stream) {
  const float* u_hat = (const float*)d_in[0];
  const int*   ei    = (const int*)d_in[1];
  const float* fn    = (const float*)d_in[2];
  const float* fa    = (const float*)d_in[3];
  const float* fd    = (const float*)d_in[4];
  const float* cv    = (const float*)d_in[5];
  float* out = (float*)d_out;

  const int N = in_sizes[0] / 3;   // 500,000
  const int E = in_sizes[1] / 2;   // 8,000,000
  const int NB = (N + BSIZE - 1) >> BSHIFT;  // coarse buckets (977)
  const int NS = NB * NBLK;        // scan length (250,112)
  const int chunk = (E + NBLK - 1) / NBLK;

  // ---- workspace bump allocator (256B aligned) ----
  char* base = (char*)d_ws;
  size_t off = 0;
  auto alloc = [&](size_t bytes) -> void* {
    void* ptr = base + off;
    off = (off + bytes + 255) & ~size_t(255);
    return ptr;
  };
  unsigned* mat   = (unsigned*)alloc((size_t)NS * 4);
  unsigned* offs  = (unsigned*)alloc((size_t)(NS + 1) * 4);
  unsigned* btot  = (unsigned*)alloc(512 * 4);
  float*    diag  = (float*)alloc((size_t)N * 4);
  float*    minv  = (float*)alloc((size_t)N * 4);
  float*    phi   = (float*)alloc((size_t)N * 4);
  float*    rvec  = (float*)alloc((size_t)N * 4);
  float*    zvec  = (float*)alloc((size_t)N * 4);
  float*    pA    = (float*)alloc((size_t)N * 4);
  float*    pB    = (float*)alloc((size_t)N * 4);
  float*    apA   = (float*)alloc((size_t)N * 4);
  float*    apB   = (float*)alloc((size_t)N * 4);
  float*    rzrr  = (float*)alloc((size_t)(2 * (CG_ITERS + 1)) * KB * 4);
  float*    papp  = (float*)alloc((size_t)CG_ITERS * KB * 4);
  uint4*    A16   = (uint4*)alloc((size_t)E * 16);      // base ≈ 150 MB
  ull* A8 = nullptr;                                    // tier 1: +64 MB
  if (off + (size_t)E * 8 + 256 <= ws_size) A8 = (ull*)alloc((size_t)E * 8);
  float2* WF = nullptr;                                 // tier 2: +64 MB
  if (off + (size_t)E * 8 + 256 <= ws_size) WF = (float2*)alloc((size_t)E * 8);
  (void)n_in; (void)out_size;

  auto rz_part = [&](int it) { return rzrr + (size_t)(2 * it) * KB; };
  auto rr_part = [&](int it) { return rzrr + (size_t)(2 * it + 1) * KB; };
  auto pap_part = [&](int it) { return papp + (size_t)it * KB; };

  const int nbScan = (NS + 1023) / 1024;          // 245 <= 512
  const int gridScanAdd = (NS + TPB - 1) / TPB;

  hist_wf<<<NBLK, TPB_A, 0, stream>>>(ei, u_hat, fn, fa, fd, mat, WF,
                                      E, NB, chunk);

  scan_blocks<<<nbScan, TPB, 0, stream>>>(mat, offs, btot, NS);
  scan_totals<<<1, 512, 0, stream>>>(btot, nbScan);
  scan_add<<<gridScanAdd, TPB, 0, stream>>>(offs, btot, NS, (unsigned)E);

  bucket_place<<<NBLK, TPB_A, 0, stream>>>(ei, u_hat, fn, fa, fd, WF, offs,
                                           A16, E, NB, chunk);

  node_setup<<<KB, TPB_B, 0, stream>>>(A16, A8, offs, cv, diag, minv,
                                       rvec, zvec, phi,
                                       rz_part(0), rr_part(0), N, NB);

  float* pbuf[2]  = {pA, pB};
  float* apbuf[2] = {apA, apB};
  for (int it = 0; it < CG_ITERS; it++) {
    int ni = it & 1;                 // new buffer index
    float* pn  = pbuf[ni];
    float* apn = apbuf[ni];
    const float* po  = pbuf[1 - ni];
    const float* apo = apbuf[1 - ni];
    int first = (it == 0) ? 1 : 0;
    matvec_az<<<NB, TPB_B, 0, stream>>>(zvec, diag, offs, A8, A16,
                                        po, pn, apo, apn, pap_part(it),
                                        rz_part(it), rz_part(it > 0 ? it - 1 : 0),
                                        rr_part(it), N, first);
    cg_update<<<KB, TPB, 0, stream>>>(phi, rvec, pn, apn, minv, zvec,
                                      pap_part(it), rz_part(it), rr_part(it),
                                      rz_part(it + 1), rr_part(it + 1), N, NB);
  }

  finalize<<<NB, TPB_B, 0, stream>>>(u_hat, cv, phi, offs, A16,
                                     fn, out, N, NB);
}